// Round 15
// baseline (213.621 us; speedup 1.0000x reference)
//
#include <hip/hip_runtime.h>
#include <hip/hip_fp16.h>

#define N_NODES 100000
#define N_EDGES 3200000
#define F_INN 512
#define NGR 256
#define BSH 6                    // bin = dst >> 6 (64 nodes per bin)
#define NBIN 1563                // ceil(N_NODES/64)
#define KBB 256                  // binning blocks (CHUNK=12500 -> ~8 recs/bin/block, 32B runs)
#define CHUNK (N_EDGES / KBB)    // 12500 exactly
#define CAP 2560                 // per-bin record capacity (mean 2048, +11 sigma)

typedef __attribute__((ext_vector_type(8))) short bf16x8;
typedef __attribute__((ext_vector_type(4))) float f32x4;

__device__ __forceinline__ uint f2bf2(float a, float b) {
  uint ua = __float_as_uint(a), ub = __float_as_uint(b);
  uint ra = (ua + 0x7FFF + ((ua >> 16) & 1)) >> 16;
  uint rb = (ub + 0x7FFF + ((ub >> 16) & 1)) >> 16;
  return ra | (rb << 16);
}

__device__ __forceinline__ void acc_h8(const __half* base, int s, int q,
                                       float& a0, float& a1, float& a2, float& a3) {
  uint2 u = *(const uint2*)(base + (size_t)s * 16 + q * 4);
  float2 f0 = __half22float2(*reinterpret_cast<__half2*>(&u.x));
  float2 f1 = __half22float2(*reinterpret_cast<__half2*>(&u.y));
  a0 += f0.x; a1 += f0.y; a2 += f1.x; a3 += f1.y;
}

// ---------------- binning + W1 transpose (round-13 proven form) ----------------
__global__ __launch_bounds__(512) void k_bin(const int* __restrict__ ei,
                                             int* __restrict__ bincur,
                                             int* __restrict__ rec,
                                             const float* __restrict__ W,
                                             ushort* __restrict__ Wt) {
  if (blockIdx.x == KBB) {
    for (int tid = threadIdx.x; tid < 16 * 512; tid += 512) {
      int n = tid >> 9;
      int k = tid & 511;
      uint u = __float_as_uint(W[k * 16 + n]);
      Wt[tid] = (ushort)((u + 0x7FFF + ((u >> 16) & 1)) >> 16);
    }
    return;
  }
  __shared__ int h[NBIN];
  __shared__ int base[NBIN];
  for (int t = threadIdx.x; t < NBIN; t += 512) h[t] = 0;
  __syncthreads();
  int e0 = blockIdx.x * CHUNK;
  for (int i = threadIdx.x; i < CHUNK; i += 512)
    atomicAdd(&h[ei[N_EDGES + e0 + i] >> BSH], 1);
  __syncthreads();
  for (int t = threadIdx.x; t < NBIN; t += 512) {
    int c = h[t];
    base[t] = t * CAP + (c ? atomicAdd(&bincur[t], c) : 0);
    h[t] = 0;                       // reuse as local cursor
  }
  __syncthreads();
  for (int i = threadIdx.x; i < CHUNK; i += 512) {
    int s = ei[e0 + i];
    int d = ei[N_EDGES + e0 + i];   // L3-hot re-read (register-caching spills: rule #20)
    int k = d >> BSH;
    int pos = base[k] + atomicAdd(&h[k], 1);
    rec[pos] = (s << BSH) | (d & 63);
  }
}

// ---------------- GEMM1 (MFMA, LDS-free stream) + per-bin degree histogram ----------------
__global__ __launch_bounds__(256) void k_gemm1(const float* __restrict__ X,
                                               const ushort* __restrict__ Wt,
                                               const int* __restrict__ rec,
                                               const int* __restrict__ bincur,
                                               __half* __restrict__ T1h) {
  __shared__ int hh[64];
  const int t = threadIdx.x;
  if (t < 64) hh[t] = 0;
  __syncthreads();
  {
    int cnt = bincur[blockIdx.x];
    const int* rb = rec + (size_t)blockIdx.x * CAP;
    for (int i = t; i < cnt; i += 256) atomicAdd(&hh[rb[i] & 63], 1);
  }

  const int lane = t & 63;
  const int w = t >> 6;
  const int c16 = lane & 15;
  const int g = lane >> 4;
  const int arow = blockIdx.x * 64 + w * 16 + c16;
  const bool rv = arow < N_NODES;
  const float* xrow = X + (size_t)arow * F_INN + g * 8;
  const ushort* brow = Wt + c16 * 512 + g * 8;

  f32x4 acc = {0.f, 0.f, 0.f, 0.f};
#pragma unroll
  for (int ks = 0; ks < 16; ++ks) {
    float4 v0 = rv ? *(const float4*)(xrow + ks * 32)     : make_float4(0.f, 0.f, 0.f, 0.f);
    float4 v1 = rv ? *(const float4*)(xrow + ks * 32 + 4) : make_float4(0.f, 0.f, 0.f, 0.f);
    uint au[4] = { f2bf2(v0.x, v0.y), f2bf2(v0.z, v0.w),
                   f2bf2(v1.x, v1.y), f2bf2(v1.z, v1.w) };
    bf16x8 a = *(const bf16x8*)au;
    bf16x8 b = *(const bf16x8*)(brow + ks * 32);
    acc = __builtin_amdgcn_mfma_f32_16x16x32_bf16(a, b, acc, 0, 0, 0);
  }

  __syncthreads();                    // histogram complete
  int lbase = w * 16 + g * 4;
  int rbase = blockIdx.x * 64 + lbase;
#pragma unroll
  for (int j = 0; j < 4; ++j) {
    int r = rbase + j;
    if (r < N_NODES) {
      float di = rsqrtf((float)hh[lbase + j] + 1.0f);
      T1h[(size_t)r * 16 + c16] = __float2half(di * acc[j]);
    }
  }
}

// ---------------- layer-1: stage+histogram -> in-LDS sort -> 4-wide register gather + bias/ReLU/W2 ----------------
__global__ __launch_bounds__(256) void k_agg1(const int* __restrict__ rec,
                                              const int* __restrict__ bincur,
                                              const __half* __restrict__ T1h,
                                              const float* __restrict__ b1,
                                              const float* __restrict__ W2,
                                              float* __restrict__ T2) {
  __shared__ int recs[CAP];
  __shared__ int recs2[CAP];
  __shared__ float accs[64 * 17];
  __shared__ int hh[64], excl[64], cur[64];
  int k = blockIdx.x, t = threadIdx.x;
  int n0 = k << BSH;
  int cnt = bincur[k];
  if (t < 64) hh[t] = 0;
  __syncthreads();
  for (int i = t; i < cnt; i += 256) {              // stage + histogram in one pass
    int v = rec[(size_t)k * CAP + i];
    recs[i] = v;
    atomicAdd(&hh[v & 63], 1);
  }
  int node = n0 + (t >> 2);
  int q = t & 3;
  bool nv = node < N_NODES;
  float a0 = 0.f, a1 = 0.f, a2 = 0.f, a3 = 0.f;
  if (nv) acc_h8(T1h, node, q, a0, a1, a2, a3);     // self-loop term
  __syncthreads();
  if (t < 64) {                                     // wave 0: shuffle exclusive scan
    int c = hh[t];
    int sc = c;
#pragma unroll
    for (int o = 1; o < 64; o <<= 1) {
      int u = __shfl_up(sc, o);
      if (t >= o) sc += u;
    }
    excl[t] = sc - c;
    cur[t] = 0;
  }
  __syncthreads();
  for (int i = t; i < cnt; i += 256) {              // LDS counting-sort scatter
    int v = recs[i];
    int dl = v & 63;
    int pos = excl[dl] + atomicAdd(&cur[dl], 1);
    recs2[pos] = v >> BSH;
  }
  __syncthreads();
  int myc = hh[t >> 2];
  int r = excl[t >> 2];
  int e = r + myc;
  for (; r + 3 < e; r += 4) {                       // 4 outstanding gathers
    int s0 = recs2[r], s1 = recs2[r + 1], s2 = recs2[r + 2], s3 = recs2[r + 3];
    acc_h8(T1h, s0, q, a0, a1, a2, a3);
    acc_h8(T1h, s1, q, a0, a1, a2, a3);
    acc_h8(T1h, s2, q, a0, a1, a2, a3);
    acc_h8(T1h, s3, q, a0, a1, a2, a3);
  }
  for (; r < e; ++r) acc_h8(T1h, recs2[r], q, a0, a1, a2, a3);
  float dd = nv ? rsqrtf((float)myc + 1.0f) : 0.f;
  float* rowp = &accs[(t >> 2) * 17 + q * 4];
  rowp[0] = dd * a0; rowp[1] = dd * a1; rowp[2] = dd * a2; rowp[3] = dd * a3;
  __syncthreads();
  if (t < 64) {
    int n = n0 + t;
    if (n < N_NODES) {
      float dd2 = rsqrtf((float)hh[t] + 1.0f);
      float s0 = 0.f, s1 = 0.f;
#pragma unroll
      for (int c = 0; c < 16; ++c) {
        float hv = fmaxf(accs[t * 17 + c] + b1[c], 0.f);
        s0 = fmaf(hv, W2[c * 2 + 0], s0);
        s1 = fmaf(hv, W2[c * 2 + 1], s1);
      }
      T2[(size_t)n * 2 + 0] = dd2 * s0;   // t2' = dinv * t2
      T2[(size_t)n * 2 + 1] = dd2 * s1;
    }
  }
}

// ---------------- layer-2: in-LDS sort -> 4-wide gather + mean-pool + last-block log_softmax ----------------
__global__ __launch_bounds__(256) void k_agg2(const int* __restrict__ rec,
                                              const int* __restrict__ bincur,
                                              const float* __restrict__ T2,
                                              const int* __restrict__ batch,
                                              const float* __restrict__ b2,
                                              float* __restrict__ pool,
                                              float* __restrict__ gcnt,
                                              int* __restrict__ ticket,
                                              float* __restrict__ out) {
  __shared__ int recs[CAP];
  __shared__ int recs2[CAP];
  __shared__ float sm[128];
  __shared__ int hh[64], excl[64], cur[64];
  __shared__ int isLast;
  int k = blockIdx.x, t = threadIdx.x;
  int n0 = k << BSH;
  int cnt = bincur[k];
  if (t < 64) hh[t] = 0;
  __syncthreads();
  for (int i = t; i < cnt; i += 256) {
    int v = rec[(size_t)k * CAP + i];
    recs[i] = v;
    atomicAdd(&hh[v & 63], 1);
  }
  __syncthreads();
  if (t < 64) {
    int c = hh[t];
    int sc = c;
#pragma unroll
    for (int o = 1; o < 64; o <<= 1) {
      int u = __shfl_up(sc, o);
      if (t >= o) sc += u;
    }
    excl[t] = sc - c;
    cur[t] = 0;
  }
  __syncthreads();
  for (int i = t; i < cnt; i += 256) {
    int v = recs[i];
    int dl = v & 63;
    int pos = excl[dl] + atomicAdd(&cur[dl], 1);
    recs2[pos] = v >> BSH;
  }
  __syncthreads();
  if (t < 128) {
    int nl = t >> 1, c = t & 1;
    int n = n0 + nl;
    bool nv = n < N_NODES;
    float acc = nv ? T2[(size_t)n * 2 + c] : 0.f;     // self loop
    int r = excl[nl], e = r + hh[nl];
    for (; r + 3 < e; r += 4) {
      int s0 = recs2[r], s1 = recs2[r + 1], s2 = recs2[r + 2], s3 = recs2[r + 3];
      acc += T2[(size_t)s0 * 2 + c] + T2[(size_t)s1 * 2 + c]
           + T2[(size_t)s2 * 2 + c] + T2[(size_t)s3 * 2 + c];
    }
    for (; r < e; ++r) acc += T2[(size_t)recs2[r] * 2 + c];
    sm[t] = nv ? rsqrtf((float)hh[nl] + 1.0f) * acc : 0.f;
  }
  __syncthreads();
  if (t < 64) {                          // wave 0 pools the block's 64 nodes
    int n = n0 + t;
    bool valid = n < N_NODES;
    int b = valid ? batch[n] : -1;
    float vx = sm[2 * t], vy = sm[2 * t + 1];
    int b0 = __shfl(b, 0);
    if (__all(b == b0)) {
      if (b0 >= 0) {
#pragma unroll
        for (int o = 32; o > 0; o >>= 1) {
          vx += __shfl_xor(vx, o);
          vy += __shfl_xor(vy, o);
        }
        if (t == 0) {
          atomicAdd(&pool[b0 * 2 + 0], vx);
          atomicAdd(&pool[b0 * 2 + 1], vy);
          atomicAdd(&gcnt[b0], 64.0f);
        }
      }
    } else if (valid) {
      atomicAdd(&pool[b * 2 + 0], vx);
      atomicAdd(&pool[b * 2 + 1], vy);
      atomicAdd(&gcnt[b], 1.0f);
    }
  }
  // ---- last block computes log_softmax (atomic RMW reads -> coherent) ----
  if (t == 0) {
    __threadfence();
    int v = atomicAdd(ticket, 1);
    isLast = (v == NBIN - 1);
  }
  __syncthreads();
  if (isLast && t < NGR) {
    float c = fmaxf(atomicAdd(&gcnt[t], 0.f), 1.0f);
    float p0 = atomicAdd(&pool[t * 2 + 0], 0.f) / c + b2[0];
    float p1 = atomicAdd(&pool[t * 2 + 1], 0.f) / c + b2[1];
    float m = fmaxf(p0, p1);
    float l = logf(expf(p0 - m) + expf(p1 - m));
    out[t * 2 + 0] = p0 - m - l;
    out[t * 2 + 1] = p1 - m - l;
  }
}

extern "C" void kernel_launch(void* const* d_in, const int* in_sizes, int n_in,
                              void* d_out, int out_size, void* d_ws, size_t ws_size,
                              hipStream_t stream) {
  const float* x  = (const float*)d_in[0];
  const float* W1 = (const float*)d_in[1];
  const float* b1 = (const float*)d_in[2];
  const float* W2 = (const float*)d_in[3];
  const float* b2 = (const float*)d_in[4];
  const int*   ei = (const int*)d_in[5];
  const int*   bt = (const int*)d_in[6];
  float* out = (float*)d_out;

  char* ws = (char*)d_ws;
  int*   bincur = (int*)ws;    ws += (size_t)NBIN * 4;
  float* pool   = (float*)ws;  ws += 2 * NGR * 4;
  float* gcnt   = (float*)ws;  ws += NGR * 4;
  int*   ticket = (int*)ws;    ws += 4 * 4;          // [bincur..ticket] one memset
  ushort* wt    = (ushort*)ws; ws += (size_t)16 * 512 * 2;
  int*   rec    = (int*)ws;    ws += (size_t)NBIN * CAP * 4;
  __half* t1h   = (__half*)ws; ws += (size_t)N_NODES * 16 * 2;
  float* t2     = (float*)ws;  ws += (size_t)N_NODES * 2 * 4;

  hipMemsetAsync(bincur, 0, (size_t)(NBIN + 3 * NGR + 4) * 4, stream);

  k_bin   <<<KBB + 1, 512, 0, stream>>>(ei, bincur, rec, W1, wt);
  k_gemm1 <<<NBIN, 256, 0, stream>>>(x, wt, rec, bincur, t1h);
  k_agg1  <<<NBIN, 256, 0, stream>>>(rec, bincur, t1h, b1, W2, t2);
  k_agg2  <<<NBIN, 256, 0, stream>>>(rec, bincur, t2, bt, b2, pool, gcnt, ticket, out);
}

// Round 16
// 178.013 us; speedup vs baseline: 1.2000x; 1.2000x over previous
//
#include <hip/hip_runtime.h>
#include <hip/hip_fp16.h>

#define N_NODES 100000
#define N_EDGES 3200000
#define F_INN 512
#define NGR 256
#define BSH 6                    // bin = dst >> 6 (64 nodes per bin)
#define NBIN 1563                // ceil(N_NODES/64)
#define KBB 256                  // binning blocks (CHUNK=12500 -> ~8 recs/bin/block, 32B runs)
#define CHUNK (N_EDGES / KBB)    // 12500 exactly
#define CAP 2560                 // per-bin record capacity (mean 2048, +11 sigma)

typedef __attribute__((ext_vector_type(8))) short bf16x8;
typedef __attribute__((ext_vector_type(4))) float f32x4;

__device__ __forceinline__ uint f2bf2(float a, float b) {
  uint ua = __float_as_uint(a), ub = __float_as_uint(b);
  uint ra = (ua + 0x7FFF + ((ua >> 16) & 1)) >> 16;
  uint rb = (ub + 0x7FFF + ((ub >> 16) & 1)) >> 16;
  return ra | (rb << 16);
}

// ---------------- binning + W1 transpose ----------------
__global__ __launch_bounds__(512) void k_bin(const int* __restrict__ ei,
                                             int* __restrict__ bincur,
                                             int* __restrict__ rec,
                                             const float* __restrict__ W,
                                             ushort* __restrict__ Wt) {
  if (blockIdx.x == KBB) {
    for (int tid = threadIdx.x; tid < 16 * 512; tid += 512) {
      int n = tid >> 9;
      int k = tid & 511;
      uint u = __float_as_uint(W[k * 16 + n]);
      Wt[tid] = (ushort)((u + 0x7FFF + ((u >> 16) & 1)) >> 16);
    }
    return;
  }
  __shared__ int h[NBIN];
  __shared__ int base[NBIN];
  for (int t = threadIdx.x; t < NBIN; t += 512) h[t] = 0;
  __syncthreads();
  int e0 = blockIdx.x * CHUNK;
  for (int i = threadIdx.x; i < CHUNK; i += 512)
    atomicAdd(&h[ei[N_EDGES + e0 + i] >> BSH], 1);
  __syncthreads();
  for (int t = threadIdx.x; t < NBIN; t += 512) {
    int c = h[t];
    base[t] = t * CAP + (c ? atomicAdd(&bincur[t], c) : 0);
    h[t] = 0;                       // reuse as local cursor
  }
  __syncthreads();
  for (int i = threadIdx.x; i < CHUNK; i += 512) {
    int s = ei[e0 + i];
    int d = ei[N_EDGES + e0 + i];
    int k = d >> BSH;
    int pos = base[k] + atomicAdd(&h[k], 1);
    rec[pos] = (s << BSH) | (d & 63);
  }
}

// ---------------- GEMM1 (MFMA, LDS-free stream) + per-bin degree histogram ----------------
__global__ __launch_bounds__(256) void k_gemm1(const float* __restrict__ X,
                                               const ushort* __restrict__ Wt,
                                               const int* __restrict__ rec,
                                               const int* __restrict__ bincur,
                                               __half* __restrict__ T1h) {
  __shared__ int hh[64];
  const int t = threadIdx.x;
  if (t < 64) hh[t] = 0;
  __syncthreads();
  {
    int cnt = bincur[blockIdx.x];
    const int* rb = rec + (size_t)blockIdx.x * CAP;
    for (int i = t; i < cnt; i += 256) atomicAdd(&hh[rb[i] & 63], 1);
  }

  const int lane = t & 63;
  const int w = t >> 6;
  const int c16 = lane & 15;
  const int g = lane >> 4;
  const int arow = blockIdx.x * 64 + w * 16 + c16;
  const bool rv = arow < N_NODES;
  const float* xrow = X + (size_t)arow * F_INN + g * 8;
  const ushort* brow = Wt + c16 * 512 + g * 8;

  f32x4 acc = {0.f, 0.f, 0.f, 0.f};
#pragma unroll
  for (int ks = 0; ks < 16; ++ks) {
    float4 v0 = rv ? *(const float4*)(xrow + ks * 32)     : make_float4(0.f, 0.f, 0.f, 0.f);
    float4 v1 = rv ? *(const float4*)(xrow + ks * 32 + 4) : make_float4(0.f, 0.f, 0.f, 0.f);
    uint au[4] = { f2bf2(v0.x, v0.y), f2bf2(v0.z, v0.w),
                   f2bf2(v1.x, v1.y), f2bf2(v1.z, v1.w) };
    bf16x8 a = *(const bf16x8*)au;
    bf16x8 b = *(const bf16x8*)(brow + ks * 32);
    acc = __builtin_amdgcn_mfma_f32_16x16x32_bf16(a, b, acc, 0, 0, 0);
  }

  __syncthreads();                    // histogram complete
  int lbase = w * 16 + g * 4;
  int rbase = blockIdx.x * 64 + lbase;
#pragma unroll
  for (int j = 0; j < 4; ++j) {
    int r = rbase + j;
    if (r < N_NODES) {
      float di = rsqrtf((float)hh[lbase + j] + 1.0f);
      T1h[(size_t)r * 16 + c16] = __float2half(di * acc[j]);
    }
  }
}

// ---------------- layer-1: stage+histogram -> in-LDS sort -> register gather + bias/ReLU/W2 ----------------
__global__ __launch_bounds__(256) void k_agg1(const int* __restrict__ rec,
                                              const int* __restrict__ bincur,
                                              const __half* __restrict__ T1h,
                                              const float* __restrict__ b1,
                                              const float* __restrict__ W2,
                                              float* __restrict__ T2) {
  __shared__ int recs[CAP];
  __shared__ int recs2[CAP];        // sorted: src index per slot
  __shared__ float accs[64 * 17];
  __shared__ int hh[64], excl[64], cur[64];
  int k = blockIdx.x, t = threadIdx.x;
  int n0 = k << BSH;
  int cnt = bincur[k];
  if (t < 64) hh[t] = 0;
  __syncthreads();
  for (int i = t; i < cnt; i += 256) {              // stage + histogram in one pass
    int v = rec[(size_t)k * CAP + i];
    recs[i] = v;
    atomicAdd(&hh[v & 63], 1);
  }
  // self-loop term (independent global load, issues early)
  int node = n0 + (t >> 2);
  int q = t & 3;
  bool nv = node < N_NODES;
  float a0 = 0.f, a1 = 0.f, a2 = 0.f, a3 = 0.f;
  if (nv) {
    uint2 u = *(const uint2*)(T1h + (size_t)node * 16 + q * 4);
    float2 f0 = __half22float2(*reinterpret_cast<__half2*>(&u.x));
    float2 f1 = __half22float2(*reinterpret_cast<__half2*>(&u.y));
    a0 = f0.x; a1 = f0.y; a2 = f1.x; a3 = f1.y;
  }
  __syncthreads();
  if (t < 64) {                                     // wave 0: shuffle exclusive scan
    int c = hh[t];
    int sc = c;
#pragma unroll
    for (int o = 1; o < 64; o <<= 1) {
      int u = __shfl_up(sc, o);
      if (t >= o) sc += u;
    }
    excl[t] = sc - c;
    cur[t] = 0;
  }
  __syncthreads();
  for (int i = t; i < cnt; i += 256) {              // LDS counting-sort scatter
    int v = recs[i];
    int dl = v & 63;
    int pos = excl[dl] + atomicAdd(&cur[dl], 1);
    recs2[pos] = v >> BSH;
  }
  __syncthreads();
  int myc = hh[t >> 2];
  int r = excl[t >> 2];
  int e = r + myc;
  for (; r + 1 < e; r += 2) {
    int s0 = recs2[r], s1 = recs2[r + 1];
    uint2 ua = *(const uint2*)(T1h + (size_t)s0 * 16 + q * 4);
    uint2 ub = *(const uint2*)(T1h + (size_t)s1 * 16 + q * 4);
    float2 fa0 = __half22float2(*reinterpret_cast<__half2*>(&ua.x));
    float2 fa1 = __half22float2(*reinterpret_cast<__half2*>(&ua.y));
    float2 fb0 = __half22float2(*reinterpret_cast<__half2*>(&ub.x));
    float2 fb1 = __half22float2(*reinterpret_cast<__half2*>(&ub.y));
    a0 += fa0.x + fb0.x; a1 += fa0.y + fb0.y;
    a2 += fa1.x + fb1.x; a3 += fa1.y + fb1.y;
  }
  if (r < e) {
    int s = recs2[r];
    uint2 u = *(const uint2*)(T1h + (size_t)s * 16 + q * 4);
    float2 f0 = __half22float2(*reinterpret_cast<__half2*>(&u.x));
    float2 f1 = __half22float2(*reinterpret_cast<__half2*>(&u.y));
    a0 += f0.x; a1 += f0.y; a2 += f1.x; a3 += f1.y;
  }
  float dd = nv ? rsqrtf((float)myc + 1.0f) : 0.f;
  float* rowp = &accs[(t >> 2) * 17 + q * 4];
  rowp[0] = dd * a0; rowp[1] = dd * a1; rowp[2] = dd * a2; rowp[3] = dd * a3;
  __syncthreads();
  if (t < 64) {
    int n = n0 + t;
    if (n < N_NODES) {
      float dd2 = rsqrtf((float)hh[t] + 1.0f);
      float s0 = 0.f, s1 = 0.f;
#pragma unroll
      for (int c = 0; c < 16; ++c) {
        float hv = fmaxf(accs[t * 17 + c] + b1[c], 0.f);
        s0 = fmaf(hv, W2[c * 2 + 0], s0);
        s1 = fmaf(hv, W2[c * 2 + 1], s1);
      }
      T2[(size_t)n * 2 + 0] = dd2 * s0;   // t2' = dinv * t2
      T2[(size_t)n * 2 + 1] = dd2 * s1;
    }
  }
}

// ---------------- layer-2: stage+histogram -> in-LDS sort -> gather + fused mean-pool ----------------
__global__ __launch_bounds__(256) void k_agg2(const int* __restrict__ rec,
                                              const int* __restrict__ bincur,
                                              const float* __restrict__ T2,
                                              const int* __restrict__ batch,
                                              float* __restrict__ pool,
                                              float* __restrict__ gcnt) {
  __shared__ int recs[CAP];
  __shared__ int recs2[CAP];
  __shared__ float sm[128];
  __shared__ int hh[64], excl[64], cur[64];
  int k = blockIdx.x, t = threadIdx.x;
  int n0 = k << BSH;
  int cnt = bincur[k];
  if (t < 64) hh[t] = 0;
  __syncthreads();
  for (int i = t; i < cnt; i += 256) {
    int v = rec[(size_t)k * CAP + i];
    recs[i] = v;
    atomicAdd(&hh[v & 63], 1);
  }
  __syncthreads();
  if (t < 64) {
    int c = hh[t];
    int sc = c;
#pragma unroll
    for (int o = 1; o < 64; o <<= 1) {
      int u = __shfl_up(sc, o);
      if (t >= o) sc += u;
    }
    excl[t] = sc - c;
    cur[t] = 0;
  }
  __syncthreads();
  for (int i = t; i < cnt; i += 256) {
    int v = recs[i];
    int dl = v & 63;
    int pos = excl[dl] + atomicAdd(&cur[dl], 1);
    recs2[pos] = v >> BSH;
  }
  __syncthreads();
  if (t < 128) {
    int nl = t >> 1, c = t & 1;
    int n = n0 + nl;
    bool nv = n < N_NODES;
    float acc = nv ? T2[(size_t)n * 2 + c] : 0.f;     // self loop
    int r = excl[nl], e = r + hh[nl];
    for (; r + 1 < e; r += 2) {
      int s0 = recs2[r], s1 = recs2[r + 1];
      acc += T2[(size_t)s0 * 2 + c] + T2[(size_t)s1 * 2 + c];
    }
    if (r < e) acc += T2[(size_t)recs2[r] * 2 + c];
    sm[t] = nv ? rsqrtf((float)hh[nl] + 1.0f) * acc : 0.f;
  }
  __syncthreads();
  if (t < 64) {                          // wave 0 pools the block's 64 nodes
    int n = n0 + t;
    bool valid = n < N_NODES;
    int b = valid ? batch[n] : -1;
    float vx = sm[2 * t], vy = sm[2 * t + 1];
    int b0 = __shfl(b, 0);
    if (__all(b == b0)) {
      if (b0 >= 0) {
#pragma unroll
        for (int o = 32; o > 0; o >>= 1) {
          vx += __shfl_xor(vx, o);
          vy += __shfl_xor(vy, o);
        }
        if (t == 0) {
          atomicAdd(&pool[b0 * 2 + 0], vx);
          atomicAdd(&pool[b0 * 2 + 1], vy);
          atomicAdd(&gcnt[b0], 64.0f);
        }
      }
    } else if (valid) {
      atomicAdd(&pool[b * 2 + 0], vx);
      atomicAdd(&pool[b * 2 + 1], vy);
      atomicAdd(&gcnt[b], 1.0f);
    }
  }
}

// ---------------- final ----------------
__global__ __launch_bounds__(256) void k_final(const float* __restrict__ pool,
                                               const float* __restrict__ gcnt,
                                               const float* __restrict__ b2,
                                               float* __restrict__ out) {
  int g = threadIdx.x;
  if (g < NGR) {
    float c = fmaxf(gcnt[g], 1.0f);
    float p0 = pool[g * 2 + 0] / c + b2[0];
    float p1 = pool[g * 2 + 1] / c + b2[1];
    float m = fmaxf(p0, p1);
    float l = logf(expf(p0 - m) + expf(p1 - m));
    out[g * 2 + 0] = p0 - m - l;
    out[g * 2 + 1] = p1 - m - l;
  }
}

extern "C" void kernel_launch(void* const* d_in, const int* in_sizes, int n_in,
                              void* d_out, int out_size, void* d_ws, size_t ws_size,
                              hipStream_t stream) {
  const float* x  = (const float*)d_in[0];
  const float* W1 = (const float*)d_in[1];
  const float* b1 = (const float*)d_in[2];
  const float* W2 = (const float*)d_in[3];
  const float* b2 = (const float*)d_in[4];
  const int*   ei = (const int*)d_in[5];
  const int*   bt = (const int*)d_in[6];
  float* out = (float*)d_out;

  char* ws = (char*)d_ws;
  int*   bincur = (int*)ws;    ws += (size_t)NBIN * 4;
  float* pool   = (float*)ws;  ws += 2 * NGR * 4;
  float* gcnt   = (float*)ws;  ws += NGR * 4;       // [bincur..gcnt] one memset
  ushort* wt    = (ushort*)ws; ws += (size_t)16 * 512 * 2;
  int*   rec    = (int*)ws;    ws += (size_t)NBIN * CAP * 4;
  __half* t1h   = (__half*)ws; ws += (size_t)N_NODES * 16 * 2;
  float* t2     = (float*)ws;  ws += (size_t)N_NODES * 2 * 4;

  hipMemsetAsync(bincur, 0, (size_t)(NBIN + 3 * NGR) * 4, stream);

  k_bin   <<<KBB + 1, 512, 0, stream>>>(ei, bincur, rec, W1, wt);
  k_gemm1 <<<NBIN, 256, 0, stream>>>(x, wt, rec, bincur, t1h);
  k_agg1  <<<NBIN, 256, 0, stream>>>(rec, bincur, t1h, b1, W2, t2);
  k_agg2  <<<NBIN, 256, 0, stream>>>(rec, bincur, t2, bt, pool, gcnt);
  k_final <<<1, 256, 0, stream>>>(pool, gcnt, b2, out);
}